// Round 9
// baseline (257.175 us; speedup 1.0000x reference)
//
#include <hip/hip_runtime.h>
#include <math.h>

#define B_SZ 16384
#define F_N 39
#define V_N 30000
#define D_N 16
#define K_SEL 20
#define FD 624     // F_N * D_N
#define KP0 640    // controller/GEMM0 K padded to multiple of 32
#define NCP 48     // controller GEMM padded N (>= 39, 3 n-tiles of 16)
#define N0 1024
#define N1 512
#define CBR 16     // batch rows per fused-controller block
#define ALD 648    // LDS row stride (u16)

typedef unsigned short u16;
typedef __attribute__((ext_vector_type(8))) short bf16x8;
typedef __attribute__((ext_vector_type(8))) unsigned short u16x8;
typedef __attribute__((ext_vector_type(4))) float f32x4;
typedef __attribute__((ext_vector_type(4))) unsigned short u16x4;

__device__ __forceinline__ u16 f2bf(float v) {
    union { float f; unsigned u; } x; x.f = v;
    unsigned r = x.u + 0x7fff + ((x.u >> 16) & 1);   // RNE
    return (u16)(r >> 16);
}
__device__ __forceinline__ float bf2f(u16 v) {
    union { unsigned u; float f; } x; x.u = ((unsigned)v) << 16;
    return x.f;
}

#define GLD16(gp, lp) __builtin_amdgcn_global_load_lds( \
    (const __attribute__((address_space(1))) unsigned int*)(gp), \
    (__attribute__((address_space(3))) unsigned int*)(lp), 16, 0, 0)

// ---------------------------------------------------------------------------
// Merged prep: w0 permute+convert, w1 convert, wc permute+convert, bn params,
// outp zeroing (replaces a separate memset launch).
// ---------------------------------------------------------------------------
#define PREP_W0 (N0 * KP0)                 // 655360
#define PREP_W1 (N1 * N0)                  // 524288
#define PREP_WC (NCP * KP0)                // 30720
#define PREP_TOT (PREP_W0 + PREP_W1 + PREP_WC + 3 * NCP + B_SZ)

__global__ __launch_bounds__(256) void prep_all_kernel(
    const float* __restrict__ w0, const float* __restrict__ w1,
    const float* __restrict__ w_c, const float* __restrict__ b_c,
    const float* __restrict__ g_c, const float* __restrict__ be_c,
    u16* __restrict__ w0b, u16* __restrict__ w1b, u16* __restrict__ wcb,
    float* __restrict__ bcp, float* __restrict__ gcp, float* __restrict__ becp,
    float* __restrict__ outp)
{
    int i = blockIdx.x * blockDim.x + threadIdx.x;
    if (i < PREP_W0) {
        int n = i / KP0, kk = i - n * KP0;
        float v = 0.f;
        if (kk < FD) v = w0[n * FD + (kk & 15) * F_N + (kk >> 4)];
        w0b[i] = f2bf(v);
        return;
    }
    i -= PREP_W0;
    if (i < PREP_W1) { w1b[i] = f2bf(w1[i]); return; }
    i -= PREP_W1;
    if (i < PREP_WC) {
        int n = i / KP0, kk = i - n * KP0;
        float v = 0.f;
        if (n < F_N && kk < FD) v = w_c[n * FD + (kk & 15) * F_N + (kk >> 4)];
        wcb[i] = f2bf(v);
        return;
    }
    i -= PREP_WC;
    if (i < 3 * NCP) {
        int which = i / NCP, n = i - which * NCP;
        float v = 0.f;
        if (n < F_N) v = (which == 0) ? b_c[n] : (which == 1) ? g_c[n] : be_c[n];
        ((which == 0) ? bcp : (which == 1) ? gcp : becp)[n] = v;
        return;
    }
    i -= 3 * NCP;
    if (i < B_SZ) outp[i] = 0.f;
}

// ---------------------------------------------------------------------------
// Fused controller: gather -> LDS, 16x48 MFMA GEMM split-K over 4 waves,
// all-wave reduce, wave-sliced bn/softmax/top-K rank, select-scale -> zb.
// ---------------------------------------------------------------------------
__global__ __launch_bounds__(256) void fused_controller_kernel(
    const int* __restrict__ x, const float* __restrict__ emb_table,
    const u16* __restrict__ wcb, const float* __restrict__ bcp,
    const float* __restrict__ gcp, const float* __restrict__ becp,
    u16* __restrict__ zb)
{
    __shared__ __align__(16) u16 Al[CBR * ALD];
    __shared__ float vv[CBR][49];
    __shared__ f32x4 part[4][64][3];
    __shared__ float selw[CBR][F_N];

    const int t    = threadIdx.x;
    const int wave = t >> 6;
    const int lane = t & 63;
    const int b0   = blockIdx.x * CBR;

    for (int p = t; p < CBR * F_N; p += 256) {
        const int row = p / F_N;
        const int f   = p - row * F_N;
        const int xi  = x[b0 * F_N + p];
        const float4* src = (const float4*)(emb_table + (size_t)(xi + f * V_N) * D_N);
        float4 v0 = src[0], v1 = src[1], v2 = src[2], v3 = src[3];
        u16x8 o0 = { f2bf(v0.x), f2bf(v0.y), f2bf(v0.z), f2bf(v0.w),
                     f2bf(v1.x), f2bf(v1.y), f2bf(v1.z), f2bf(v1.w) };
        u16x8 o1 = { f2bf(v2.x), f2bf(v2.y), f2bf(v2.z), f2bf(v2.w),
                     f2bf(v3.x), f2bf(v3.y), f2bf(v3.z), f2bf(v3.w) };
        *(u16x8*)&Al[row * ALD + f * D_N]     = o0;
        *(u16x8*)&Al[row * ALD + f * D_N + 8] = o1;
    }
    __syncthreads();

    const int m = lane & 15;
    const int q = lane >> 4;
    f32x4 acc0 = {}, acc1 = {}, acc2 = {};
    {
        const u16* ap  = &Al[m * ALD + wave * 160 + q * 8];
        const u16* bp0 = wcb + (size_t)(0  + m) * KP0 + wave * 160 + q * 8;
        const u16* bp1 = wcb + (size_t)(16 + m) * KP0 + wave * 160 + q * 8;
        const u16* bp2 = wcb + (size_t)(32 + m) * KP0 + wave * 160 + q * 8;
        #pragma unroll
        for (int k = 0; k < 5; ++k) {
            bf16x8 af = *(const bf16x8*)ap;
            bf16x8 b0 = *(const bf16x8*)bp0;
            bf16x8 b1 = *(const bf16x8*)bp1;
            bf16x8 b2 = *(const bf16x8*)bp2;
            acc0 = __builtin_amdgcn_mfma_f32_16x16x32_bf16(af, b0, acc0, 0, 0, 0);
            acc1 = __builtin_amdgcn_mfma_f32_16x16x32_bf16(af, b1, acc1, 0, 0, 0);
            acc2 = __builtin_amdgcn_mfma_f32_16x16x32_bf16(af, b2, acc2, 0, 0, 0);
            ap += 32; bp0 += 32; bp1 += 32; bp2 += 32;
        }
    }
    part[wave][lane][0] = acc0;
    part[wave][lane][1] = acc1;
    part[wave][lane][2] = acc2;
    __syncthreads();

    {
        f32x4 r0 = part[0][lane][0] + part[1][lane][0] + part[2][lane][0] + part[3][lane][0];
        f32x4 r1 = part[0][lane][1] + part[1][lane][1] + part[2][lane][1] + part[3][lane][1];
        f32x4 r2 = part[0][lane][2] + part[1][lane][2] + part[2][lane][2] + part[3][lane][2];

        const float rs = rsqrtf(1.0f + 1e-5f);
        if (q == wave) {
            #pragma unroll
            for (int j = 0; j < 3; ++j) {
                const f32x4 a = (j == 0) ? r0 : (j == 1) ? r1 : r2;
                const int n = j * 16 + m;
                const float gn = gcp[n] * rs;
                const float bn = becp[n];
                const float bi = bcp[n];
                #pragma unroll
                for (int r = 0; r < 4; ++r)
                    vv[wave * 4 + r][n] = fmaxf(fmaf(gn, a[r] + bi, bn), 0.f);
            }
        }
    }
    __syncthreads();

    {
        const int row = wave * 4 + (lane >> 4);
        const int fl  = lane & 15;
        float e[3] = {0.f, 0.f, 0.f};
        float mloc = -1e30f;
        #pragma unroll
        for (int it = 0; it < 3; ++it) {
            const int f = fl + 16 * it;
            if (f < F_N) { e[it] = vv[row][f]; mloc = fmaxf(mloc, e[it]); }
        }
        mloc = fmaxf(mloc, __shfl_xor(mloc, 1, 64));
        mloc = fmaxf(mloc, __shfl_xor(mloc, 2, 64));
        mloc = fmaxf(mloc, __shfl_xor(mloc, 4, 64));
        mloc = fmaxf(mloc, __shfl_xor(mloc, 8, 64));
        float sloc = 0.f;
        #pragma unroll
        for (int it = 0; it < 3; ++it) {
            const int f = fl + 16 * it;
            if (f < F_N) { e[it] = expf(e[it] - mloc); sloc += e[it]; }
        }
        sloc += __shfl_xor(sloc, 1, 64);
        sloc += __shfl_xor(sloc, 2, 64);
        sloc += __shfl_xor(sloc, 4, 64);
        sloc += __shfl_xor(sloc, 8, 64);
        const float inv = 1.f / sloc;
        #pragma unroll
        for (int it = 0; it < 3; ++it) {
            const int f = fl + 16 * it;
            if (f < F_N) vv[row][f] = e[it];
        }

        int rank[3] = {};
        for (int gg = 0; gg < F_N; ++gg) {
            const float o = vv[row][gg];
            #pragma unroll
            for (int it = 0; it < 3; ++it) {
                const int f = fl + 16 * it;
                if (f < F_N)
                    rank[it] += (o > e[it] || (o == e[it] && gg < f)) ? 1 : 0;
            }
        }
        #pragma unroll
        for (int it = 0; it < 3; ++it) {
            const int f = fl + 16 * it;
            if (f < F_N)
                selw[row][f] = (rank[it] < K_SEL) ? e[it] * inv : 0.f;
        }
    }
    __syncthreads();

    for (int gp = t; gp < CBR * 40; gp += 256) {
        const int row  = gp & 15;
        const int slot = gp >> 4;
        u16* dst = zb + (size_t)(b0 + row) * KP0 + slot * D_N;
        u16x8 o0 = {0,0,0,0,0,0,0,0}, o1 = {0,0,0,0,0,0,0,0};
        if (slot < F_N) {
            const float w = selw[row][slot];
            u16x8 a0 = *(u16x8*)&Al[row * ALD + slot * D_N];
            u16x8 a1 = *(u16x8*)&Al[row * ALD + slot * D_N + 8];
            #pragma unroll
            for (int k = 0; k < 8; ++k) {
                o0[k] = f2bf(bf2f(a0[k]) * w);
                o1[k] = f2bf(bf2f(a1[k]) * w);
            }
        }
        *(u16x8*)dst = o0;
        *(u16x8*)(dst + 8) = o1;
    }
}

// ---------------------------------------------------------------------------
// B-direct MFMA GEMM, 128x128 tile, BK=32, K fully unrolled (template KP).
// A: double-buffered LDS via global_load_lds (8 KB/iter, drained one full
// iteration after issue). B: per-lane bf16x8 loads straight from global
// (L2-resident weights) -- pipelined by vmcnt scoreboarding, not barriers.
// MODE 0: store bf16 C. MODE 1: fused w_out dot + atomicAdd row partials.
// ---------------------------------------------------------------------------
template<int MODE, int KP>
__global__ __launch_bounds__(256) void gemm_mfma_bn_relu(
    const u16* __restrict__ A, const u16* __restrict__ W,
    const float* __restrict__ bias, const float* __restrict__ g,
    const float* __restrict__ be, u16* __restrict__ Cout,
    int M, int N,
    const float* __restrict__ w_out, float* __restrict__ outp)
{
    __shared__ __align__(16) u16 As[2][128 * 32];

    const int t    = threadIdx.x;
    const int wave = t >> 6;
    const int lane = t & 63;
    const int wm   = wave >> 1, wn = wave & 1;
    const int m0   = blockIdx.x * 128;   // M fastest -> XCD-local A reuse
    const int n0   = blockIdx.y * 128;

    const int lr    = lane >> 2;
    const int swz_u = (lane & 3) ^ ((lane >> 3) & 3);
    const u16* gA = A + (size_t)(m0 + wave * 32 + lr) * KP + swz_u * 8;
    const int oA0 = (wave * 32) * 32;
    const int oA1 = (wave * 32 + 16) * 32;

    const int q    = lane >> 4;
    const int lr16 = lane & 15;

    int aoff[4];
    const u16* bp[4];
    #pragma unroll
    for (int i = 0; i < 4; ++i) {
        int ra = wm * 64 + i * 16 + lr16;
        aoff[i] = ra * 32 + ((q ^ ((ra >> 1) & 3)) * 8);
        bp[i] = W + (size_t)(n0 + wn * 64 + i * 16 + lr16) * KP + q * 8;
    }

    // prologue: stage tile 0 into buffer 0
    GLD16(gA,           &As[0][oA0]);
    GLD16(gA + 16 * KP, &As[0][oA1]);

    f32x4 acc[4][4] = {};

    #pragma unroll
    for (int it = 0; it < KP / 32; ++it) {
        const int k0  = it * 32;
        const int buf = it & 1;
        __syncthreads();   // drains A-prefetch issued a full iteration ago
        if (it + 1 < KP / 32) {
            GLD16(gA + (k0 + 32),           &As[buf ^ 1][oA0]);
            GLD16(gA + (k0 + 32) + 16 * KP, &As[buf ^ 1][oA1]);
        }

        bf16x8 bfr[4];
        #pragma unroll
        for (int j = 0; j < 4; ++j) bfr[j] = *(const bf16x8*)(bp[j] + k0);
        bf16x8 af[4];
        #pragma unroll
        for (int i = 0; i < 4; ++i) af[i] = *(const bf16x8*)&As[buf][aoff[i]];

        #pragma unroll
        for (int i = 0; i < 4; ++i)
            #pragma unroll
            for (int j = 0; j < 4; ++j)
                acc[i][j] = __builtin_amdgcn_mfma_f32_16x16x32_bf16(
                    af[i], bfr[j], acc[i][j], 0, 0, 0);
    }

    const float rs = rsqrtf(1.0f + 1e-5f);
    if (MODE == 0) {
        #pragma unroll
        for (int j = 0; j < 4; ++j) {
            const int n = n0 + wn * 64 + j * 16 + lr16;
            const float bn_g = g[n] * rs;
            const float bn_b = be[n];
            const float bi   = bias[n];
            #pragma unroll
            for (int i = 0; i < 4; ++i) {
                const int mbase = m0 + wm * 64 + i * 16 + q * 4;
                #pragma unroll
                for (int r = 0; r < 4; ++r) {
                    float v = acc[i][j][r] + bi;
                    v = fmaxf(fmaf(bn_g, v, bn_b), 0.f);
                    Cout[(size_t)(mbase + r) * N + n] = f2bf(v);
                }
            }
        }
    } else {
        float s[4][4] = {};
        #pragma unroll
        for (int j = 0; j < 4; ++j) {
            const int n = n0 + wn * 64 + j * 16 + lr16;
            const float bn_g = g[n] * rs;
            const float bn_b = be[n];
            const float bi   = bias[n];
            const float wo   = w_out[n];
            #pragma unroll
            for (int i = 0; i < 4; ++i)
                #pragma unroll
                for (int r = 0; r < 4; ++r) {
                    float v = acc[i][j][r] + bi;
                    v = fmaxf(fmaf(bn_g, v, bn_b), 0.f);
                    s[i][r] = fmaf(v, wo, s[i][r]);
                }
        }
        #pragma unroll
        for (int i = 0; i < 4; ++i)
            #pragma unroll
            for (int r = 0; r < 4; ++r) {
                float v = s[i][r];
                v += __shfl_xor(v, 1, 64);
                v += __shfl_xor(v, 2, 64);
                v += __shfl_xor(v, 4, 64);
                v += __shfl_xor(v, 8, 64);
                s[i][r] = v;
            }
        if (lr16 == 0) {
            #pragma unroll
            for (int i = 0; i < 4; ++i) {
                const int mbase = m0 + wm * 64 + i * 16 + q * 4;
                #pragma unroll
                for (int r = 0; r < 4; ++r)
                    atomicAdd(&outp[mbase + r], s[i][r]);
            }
        }
    }
}

// ---------------------------------------------------------------------------
// out[b] = sigmoid(outp[b] + b_out)
// ---------------------------------------------------------------------------
__global__ __launch_bounds__(256) void sigmoid_kernel(
    const float* __restrict__ outp, const float* __restrict__ b_out,
    float* __restrict__ out)
{
    const int b = blockIdx.x * 256 + threadIdx.x;
    out[b] = 1.f / (1.f + expf(-(outp[b] + b_out[0])));
}

// ---------------------------------------------------------------------------
extern "C" void kernel_launch(void* const* d_in, const int* in_sizes, int n_in,
                              void* d_out, int out_size, void* d_ws, size_t ws_size,
                              hipStream_t stream)
{
    const int*   x     = (const int*)  d_in[0];
    const float* emb   = (const float*)d_in[1];
    const float* w_c   = (const float*)d_in[2];
    const float* b_c   = (const float*)d_in[3];
    const float* g_c   = (const float*)d_in[4];
    const float* be_c  = (const float*)d_in[5];
    const float* w0    = (const float*)d_in[6];
    const float* b0    = (const float*)d_in[7];
    const float* g0    = (const float*)d_in[8];
    const float* be0   = (const float*)d_in[9];
    const float* w1    = (const float*)d_in[10];
    const float* b1    = (const float*)d_in[11];
    const float* g1    = (const float*)d_in[12];
    const float* be1   = (const float*)d_in[13];
    const float* w_out = (const float*)d_in[14];
    const float* b_out = (const float*)d_in[15];
    float* out = (float*)d_out;

    // workspace layout (~57 MB)
    u16*   zb    = (u16*)d_ws;                          // B*640*2  = 20.97 MB
    u16*   w0b   = zb    + (size_t)B_SZ * KP0;          // 1.31 MB
    u16*   h0b   = w0b   + (size_t)N0 * KP0;            // 33.55 MB
    u16*   w1b   = h0b   + (size_t)B_SZ * N0;           // 1.05 MB
    u16*   wcb   = w1b   + (size_t)N1 * N0;             // 0.06 MB
    float* outp  = (float*)(wcb + (size_t)NCP * KP0);   // 64 KB
    float* bcp   = outp + B_SZ;
    float* gcp   = bcp + NCP;
    float* becp  = gcp + NCP;

    prep_all_kernel<<<(PREP_TOT + 255) / 256, 256, 0, stream>>>(
        w0, w1, w_c, b_c, g_c, be_c, w0b, w1b, wcb, bcp, gcp, becp, outp);

    fused_controller_kernel<<<B_SZ / CBR, 256, 0, stream>>>(
        x, emb, wcb, bcp, gcp, becp, zb);

    gemm_mfma_bn_relu<0, KP0><<<dim3(B_SZ / 128, N0 / 128), 256, 0, stream>>>(
        zb, w0b, b0, g0, be0, h0b, B_SZ, N0, nullptr, nullptr);

    gemm_mfma_bn_relu<1, N0><<<dim3(B_SZ / 128, N1 / 128), 256, 0, stream>>>(
        h0b, w1b, b1, g1, be1, nullptr, B_SZ, N1, w_out, outp);

    sigmoid_kernel<<<B_SZ / 256, 256, 0, stream>>>(outp, b_out, out);
}

// Round 10
// 228.535 us; speedup vs baseline: 1.1253x; 1.1253x over previous
//
#include <hip/hip_runtime.h>
#include <math.h>

#define B_SZ 16384
#define F_N 39
#define V_N 30000
#define D_N 16
#define K_SEL 20
#define FD 624     // F_N * D_N
#define KP0 640    // controller/GEMM0 K padded to multiple of 32
#define NCP 48     // controller GEMM padded N (>= 39, 3 n-tiles of 16)
#define N0 1024
#define N1 512
#define CBR 16     // batch rows per fused-controller block
#define ALD 648    // LDS row stride (u16)

typedef unsigned short u16;
typedef __attribute__((ext_vector_type(8))) short bf16x8;
typedef __attribute__((ext_vector_type(8))) unsigned short u16x8;
typedef __attribute__((ext_vector_type(4))) float f32x4;
typedef __attribute__((ext_vector_type(4))) unsigned short u16x4;

__device__ __forceinline__ u16 f2bf(float v) {
    union { float f; unsigned u; } x; x.f = v;
    unsigned r = x.u + 0x7fff + ((x.u >> 16) & 1);   // RNE
    return (u16)(r >> 16);
}
__device__ __forceinline__ float bf2f(u16 v) {
    union { unsigned u; float f; } x; x.u = ((unsigned)v) << 16;
    return x.f;
}

#define GLD16(gp, lp) __builtin_amdgcn_global_load_lds( \
    (const __attribute__((address_space(1))) unsigned int*)(gp), \
    (__attribute__((address_space(3))) unsigned int*)(lp), 16, 0, 0)

// ---------------------------------------------------------------------------
// Merged prep: w0 permute+convert, w1 convert, wc permute+convert, bn params,
// outp zeroing.
// ---------------------------------------------------------------------------
#define PREP_W0 (N0 * KP0)                 // 655360
#define PREP_W1 (N1 * N0)                  // 524288
#define PREP_WC (NCP * KP0)                // 30720
#define PREP_TOT (PREP_W0 + PREP_W1 + PREP_WC + 3 * NCP + B_SZ)

__global__ __launch_bounds__(256) void prep_all_kernel(
    const float* __restrict__ w0, const float* __restrict__ w1,
    const float* __restrict__ w_c, const float* __restrict__ b_c,
    const float* __restrict__ g_c, const float* __restrict__ be_c,
    u16* __restrict__ w0b, u16* __restrict__ w1b, u16* __restrict__ wcb,
    float* __restrict__ bcp, float* __restrict__ gcp, float* __restrict__ becp,
    float* __restrict__ outp)
{
    int i = blockIdx.x * blockDim.x + threadIdx.x;
    if (i < PREP_W0) {
        int n = i / KP0, kk = i - n * KP0;
        float v = 0.f;
        if (kk < FD) v = w0[n * FD + (kk & 15) * F_N + (kk >> 4)];
        w0b[i] = f2bf(v);
        return;
    }
    i -= PREP_W0;
    if (i < PREP_W1) { w1b[i] = f2bf(w1[i]); return; }
    i -= PREP_W1;
    if (i < PREP_WC) {
        int n = i / KP0, kk = i - n * KP0;
        float v = 0.f;
        if (n < F_N && kk < FD) v = w_c[n * FD + (kk & 15) * F_N + (kk >> 4)];
        wcb[i] = f2bf(v);
        return;
    }
    i -= PREP_WC;
    if (i < 3 * NCP) {
        int which = i / NCP, n = i - which * NCP;
        float v = 0.f;
        if (n < F_N) v = (which == 0) ? b_c[n] : (which == 1) ? g_c[n] : be_c[n];
        ((which == 0) ? bcp : (which == 1) ? gcp : becp)[n] = v;
        return;
    }
    i -= 3 * NCP;
    if (i < B_SZ) outp[i] = 0.f;
}

// ---------------------------------------------------------------------------
// Fused controller: gather -> LDS (hoisted x-loads), 16x48 MFMA split-K GEMM,
// all-wave reduce, wave-sliced bn/softmax/top-K rank, select-scale -> zb.
// ---------------------------------------------------------------------------
__global__ __launch_bounds__(256) void fused_controller_kernel(
    const int* __restrict__ x, const float* __restrict__ emb_table,
    const u16* __restrict__ wcb, const float* __restrict__ bcp,
    const float* __restrict__ gcp, const float* __restrict__ becp,
    u16* __restrict__ zb)
{
    __shared__ __align__(16) u16 Al[CBR * ALD];
    __shared__ float vv[CBR][49];
    __shared__ f32x4 part[4][64][3];
    __shared__ float selw[CBR][F_N];

    const int t    = threadIdx.x;
    const int wave = t >> 6;
    const int lane = t & 63;
    const int b0   = blockIdx.x * CBR;

    // ---- gather: 3 explicit slots, all x-loads hoisted before emb-loads ----
    {
        const int p0 = t, p1 = t + 256, p2 = t + 512;
        const int xi0 = x[b0 * F_N + p0];
        const int xi1 = x[b0 * F_N + p1];
        const int xi2 = (p2 < CBR * F_N) ? x[b0 * F_N + p2] : 0;
        const int pp[3] = { p0, p1, p2 };
        const int xx[3] = { xi0, xi1, xi2 };
        #pragma unroll
        for (int s = 0; s < 3; ++s) {
            const int p = pp[s];
            if (p < CBR * F_N) {
                const int row = p / F_N;
                const int f   = p - row * F_N;
                const float4* src =
                    (const float4*)(emb_table + (size_t)(xx[s] + f * V_N) * D_N);
                float4 v0 = src[0], v1 = src[1], v2 = src[2], v3 = src[3];
                u16x8 o0 = { f2bf(v0.x), f2bf(v0.y), f2bf(v0.z), f2bf(v0.w),
                             f2bf(v1.x), f2bf(v1.y), f2bf(v1.z), f2bf(v1.w) };
                u16x8 o1 = { f2bf(v2.x), f2bf(v2.y), f2bf(v2.z), f2bf(v2.w),
                             f2bf(v3.x), f2bf(v3.y), f2bf(v3.z), f2bf(v3.w) };
                *(u16x8*)&Al[row * ALD + f * D_N]     = o0;
                *(u16x8*)&Al[row * ALD + f * D_N + 8] = o1;
            }
        }
    }
    __syncthreads();

    const int m = lane & 15;
    const int q = lane >> 4;
    f32x4 acc0 = {}, acc1 = {}, acc2 = {};
    {
        const u16* ap  = &Al[m * ALD + wave * 160 + q * 8];
        const u16* bp0 = wcb + (size_t)(0  + m) * KP0 + wave * 160 + q * 8;
        const u16* bp1 = wcb + (size_t)(16 + m) * KP0 + wave * 160 + q * 8;
        const u16* bp2 = wcb + (size_t)(32 + m) * KP0 + wave * 160 + q * 8;
        #pragma unroll
        for (int k = 0; k < 5; ++k) {
            bf16x8 af = *(const bf16x8*)ap;
            bf16x8 b0 = *(const bf16x8*)bp0;
            bf16x8 b1 = *(const bf16x8*)bp1;
            bf16x8 b2 = *(const bf16x8*)bp2;
            acc0 = __builtin_amdgcn_mfma_f32_16x16x32_bf16(af, b0, acc0, 0, 0, 0);
            acc1 = __builtin_amdgcn_mfma_f32_16x16x32_bf16(af, b1, acc1, 0, 0, 0);
            acc2 = __builtin_amdgcn_mfma_f32_16x16x32_bf16(af, b2, acc2, 0, 0, 0);
            ap += 32; bp0 += 32; bp1 += 32; bp2 += 32;
        }
    }
    part[wave][lane][0] = acc0;
    part[wave][lane][1] = acc1;
    part[wave][lane][2] = acc2;
    __syncthreads();

    {
        f32x4 r0 = part[0][lane][0] + part[1][lane][0] + part[2][lane][0] + part[3][lane][0];
        f32x4 r1 = part[0][lane][1] + part[1][lane][1] + part[2][lane][1] + part[3][lane][1];
        f32x4 r2 = part[0][lane][2] + part[1][lane][2] + part[2][lane][2] + part[3][lane][2];

        const float rs = rsqrtf(1.0f + 1e-5f);
        if (q == wave) {
            #pragma unroll
            for (int j = 0; j < 3; ++j) {
                const f32x4 a = (j == 0) ? r0 : (j == 1) ? r1 : r2;
                const int n = j * 16 + m;
                const float gn = gcp[n] * rs;
                const float bn = becp[n];
                const float bi = bcp[n];
                #pragma unroll
                for (int r = 0; r < 4; ++r)
                    vv[wave * 4 + r][n] = fmaxf(fmaf(gn, a[r] + bi, bn), 0.f);
            }
        }
    }
    __syncthreads();

    {
        const int row = wave * 4 + (lane >> 4);
        const int fl  = lane & 15;
        float e[3] = {0.f, 0.f, 0.f};
        float mloc = -1e30f;
        #pragma unroll
        for (int it = 0; it < 3; ++it) {
            const int f = fl + 16 * it;
            if (f < F_N) { e[it] = vv[row][f]; mloc = fmaxf(mloc, e[it]); }
        }
        mloc = fmaxf(mloc, __shfl_xor(mloc, 1, 64));
        mloc = fmaxf(mloc, __shfl_xor(mloc, 2, 64));
        mloc = fmaxf(mloc, __shfl_xor(mloc, 4, 64));
        mloc = fmaxf(mloc, __shfl_xor(mloc, 8, 64));
        float sloc = 0.f;
        #pragma unroll
        for (int it = 0; it < 3; ++it) {
            const int f = fl + 16 * it;
            if (f < F_N) { e[it] = expf(e[it] - mloc); sloc += e[it]; }
        }
        sloc += __shfl_xor(sloc, 1, 64);
        sloc += __shfl_xor(sloc, 2, 64);
        sloc += __shfl_xor(sloc, 4, 64);
        sloc += __shfl_xor(sloc, 8, 64);
        const float inv = 1.f / sloc;
        #pragma unroll
        for (int it = 0; it < 3; ++it) {
            const int f = fl + 16 * it;
            if (f < F_N) vv[row][f] = e[it];
        }

        int rank[3] = {};
        for (int gg = 0; gg < F_N; ++gg) {
            const float o = vv[row][gg];
            #pragma unroll
            for (int it = 0; it < 3; ++it) {
                const int f = fl + 16 * it;
                if (f < F_N)
                    rank[it] += (o > e[it] || (o == e[it] && gg < f)) ? 1 : 0;
            }
        }
        #pragma unroll
        for (int it = 0; it < 3; ++it) {
            const int f = fl + 16 * it;
            if (f < F_N)
                selw[row][f] = (rank[it] < K_SEL) ? e[it] * inv : 0.f;
        }
    }
    __syncthreads();

    for (int gp = t; gp < CBR * 40; gp += 256) {
        const int row  = gp & 15;
        const int slot = gp >> 4;
        u16* dst = zb + (size_t)(b0 + row) * KP0 + slot * D_N;
        u16x8 o0 = {0,0,0,0,0,0,0,0}, o1 = {0,0,0,0,0,0,0,0};
        if (slot < F_N) {
            const float w = selw[row][slot];
            u16x8 a0 = *(u16x8*)&Al[row * ALD + slot * D_N];
            u16x8 a1 = *(u16x8*)&Al[row * ALD + slot * D_N + 8];
            #pragma unroll
            for (int k = 0; k < 8; ++k) {
                o0[k] = f2bf(bf2f(a0[k]) * w);
                o1[k] = f2bf(bf2f(a1[k]) * w);
            }
        }
        *(u16x8*)dst = o0;
        *(u16x8*)(dst + 8) = o1;
    }
}

// ---------------------------------------------------------------------------
// GEMM0: 256x128 tile, BK=32, dbuf LDS, 1 barrier/iter. 32 MFMA/wave/iter
// amortizes the barrier drain 2x vs the 128-tile. 48 KB LDS, 2 blocks/CU.
// C = relu(bn(A@W^T+bias)) stored bf16.
// ---------------------------------------------------------------------------
__global__ __launch_bounds__(256) void gemm0_256_kernel(
    const u16* __restrict__ A, const u16* __restrict__ W,
    const float* __restrict__ bias, const float* __restrict__ g,
    const float* __restrict__ be, u16* __restrict__ Cout,
    int M, int N, int Kp)
{
    __shared__ __align__(16) u16 As[2][256 * 32];
    __shared__ __align__(16) u16 Bs[2][128 * 32];

    const int t    = threadIdx.x;
    const int wave = t >> 6;
    const int lane = t & 63;
    const int m0   = blockIdx.x * 256;   // M fastest -> XCD-local A reuse
    const int n0   = blockIdx.y * 128;

    const int lr    = lane >> 2;
    const int swz_u = (lane & 3) ^ ((lane >> 3) & 3);
    const u16* gA = A + (size_t)(m0 + wave * 64 + lr) * Kp + swz_u * 8;
    const u16* gB = W + (size_t)(n0 + wave * 32 + lr) * Kp + swz_u * 8;
    const size_t kst = 16 * (size_t)Kp;
    const int oA = (wave * 64) * 32;
    const int oB = (wave * 32) * 32;

    const int q    = lane >> 4;
    const int lr16 = lane & 15;

    int aoff[4], boff[8];
    #pragma unroll
    for (int i = 0; i < 4; ++i) {
        int ra = wave * 64 + i * 16 + lr16;
        aoff[i] = ra * 32 + ((q ^ ((ra >> 1) & 3)) * 8);
    }
    #pragma unroll
    for (int j = 0; j < 8; ++j) {
        int rb = j * 16 + lr16;
        boff[j] = rb * 32 + ((q ^ ((rb >> 1) & 3)) * 8);
    }

    // prologue: stage tile 0 into buffer 0 (wave: 4 A-groups + 2 B-groups)
    #pragma unroll
    for (int kk = 0; kk < 4; ++kk) GLD16(gA + kk * kst, &As[0][oA + kk * 16 * 32]);
    #pragma unroll
    for (int kk = 0; kk < 2; ++kk) GLD16(gB + kk * kst, &Bs[0][oB + kk * 16 * 32]);
    gA += 32; gB += 32;

    f32x4 acc[4][8] = {};

    for (int k0 = 0; k0 < Kp; k0 += 32) {
        const int buf = (k0 >> 5) & 1;
        __syncthreads();   // drains prefetch issued a full iteration ago
        if (k0 + 32 < Kp) {
            #pragma unroll
            for (int kk = 0; kk < 4; ++kk)
                GLD16(gA + kk * kst, &As[buf ^ 1][oA + kk * 16 * 32]);
            #pragma unroll
            for (int kk = 0; kk < 2; ++kk)
                GLD16(gB + kk * kst, &Bs[buf ^ 1][oB + kk * 16 * 32]);
            gA += 32; gB += 32;
        }

        bf16x8 af[4], bfr[8];
        #pragma unroll
        for (int i = 0; i < 4; ++i) af[i]  = *(const bf16x8*)&As[buf][aoff[i]];
        #pragma unroll
        for (int j = 0; j < 8; ++j) bfr[j] = *(const bf16x8*)&Bs[buf][boff[j]];

        #pragma unroll
        for (int i = 0; i < 4; ++i)
            #pragma unroll
            for (int j = 0; j < 8; ++j)
                acc[i][j] = __builtin_amdgcn_mfma_f32_16x16x32_bf16(
                    af[i], bfr[j], acc[i][j], 0, 0, 0);
    }

    const float rs = rsqrtf(1.0f + 1e-5f);
    #pragma unroll
    for (int j = 0; j < 8; ++j) {
        const int n = n0 + j * 16 + lr16;
        const float bn_g = g[n] * rs;
        const float bn_b = be[n];
        const float bi   = bias[n];
        #pragma unroll
        for (int i = 0; i < 4; ++i) {
            const int mbase = m0 + wave * 64 + i * 16 + q * 4;
            #pragma unroll
            for (int r = 0; r < 4; ++r) {
                float v = acc[i][j][r] + bi;
                v = fmaxf(fmaf(bn_g, v, bn_b), 0.f);
                Cout[(size_t)(mbase + r) * N + n] = f2bf(v);
            }
        }
    }
}

// ---------------------------------------------------------------------------
// GEMM1 (round-8 structure): 128x128, BK=32, dbuf LDS, 1 barrier/iter.
// Fused epilogue: w_out dot + shuffle reduce + atomicAdd row partials.
// ---------------------------------------------------------------------------
__global__ __launch_bounds__(256) void gemm1_fused_out_kernel(
    const u16* __restrict__ A, const u16* __restrict__ W,
    const float* __restrict__ bias, const float* __restrict__ g,
    const float* __restrict__ be, int M, int N, int Kp,
    const float* __restrict__ w_out, float* __restrict__ outp)
{
    __shared__ __align__(16) u16 As[2][128 * 32];
    __shared__ __align__(16) u16 Bs[2][128 * 32];

    const int t    = threadIdx.x;
    const int wave = t >> 6;
    const int lane = t & 63;
    const int wm   = wave >> 1, wn = wave & 1;
    const int m0   = blockIdx.x * 128;
    const int n0   = blockIdx.y * 128;

    const int lr    = lane >> 2;
    const int swz_u = (lane & 3) ^ ((lane >> 3) & 3);
    const u16* gA0 = A + (size_t)(m0 + wave * 32 + lr) * Kp + swz_u * 8;
    const u16* gB0 = W + (size_t)(n0 + wave * 32 + lr) * Kp + swz_u * 8;
    const size_t kstep16 = 16 * (size_t)Kp;
    const int oA0 = (wave * 32) * 32;
    const int oA1 = (wave * 32 + 16) * 32;

    const int q    = lane >> 4;
    const int lr16 = lane & 15;

    int aoff[4], boff[4];
    #pragma unroll
    for (int i = 0; i < 4; ++i) {
        int ra = wm * 64 + i * 16 + lr16;
        aoff[i] = ra * 32 + ((q ^ ((ra >> 1) & 3)) * 8);
        int rb = wn * 64 + i * 16 + lr16;
        boff[i] = rb * 32 + ((q ^ ((rb >> 1) & 3)) * 8);
    }

    GLD16(gA0,           &As[0][oA0]);
    GLD16(gA0 + kstep16, &As[0][oA1]);
    GLD16(gB0,           &Bs[0][oA0]);
    GLD16(gB0 + kstep16, &Bs[0][oA1]);
    gA0 += 32; gB0 += 32;

    f32x4 acc[4][4] = {};

    for (int k0 = 0; k0 < Kp; k0 += 32) {
        const int buf = (k0 >> 5) & 1;
        __syncthreads();
        if (k0 + 32 < Kp) {
            GLD16(gA0,           &As[buf ^ 1][oA0]);
            GLD16(gA0 + kstep16, &As[buf ^ 1][oA1]);
            GLD16(gB0,           &Bs[buf ^ 1][oA0]);
            GLD16(gB0 + kstep16, &Bs[buf ^ 1][oA1]);
            gA0 += 32; gB0 += 32;
        }

        bf16x8 af[4], bfr[4];
        #pragma unroll
        for (int i = 0; i < 4; ++i) af[i]  = *(const bf16x8*)&As[buf][aoff[i]];
        #pragma unroll
        for (int j = 0; j < 4; ++j) bfr[j] = *(const bf16x8*)&Bs[buf][boff[j]];

        #pragma unroll
        for (int i = 0; i < 4; ++i)
            #pragma unroll
            for (int j = 0; j < 4; ++j)
                acc[i][j] = __builtin_amdgcn_mfma_f32_16x16x32_bf16(
                    af[i], bfr[j], acc[i][j], 0, 0, 0);
    }

    const float rs = rsqrtf(1.0f + 1e-5f);
    float s[4][4] = {};
    #pragma unroll
    for (int j = 0; j < 4; ++j) {
        const int n = n0 + wn * 64 + j * 16 + lr16;
        const float bn_g = g[n] * rs;
        const float bn_b = be[n];
        const float bi   = bias[n];
        const float wo   = w_out[n];
        #pragma unroll
        for (int i = 0; i < 4; ++i)
            #pragma unroll
            for (int r = 0; r < 4; ++r) {
                float v = acc[i][j][r] + bi;
                v = fmaxf(fmaf(bn_g, v, bn_b), 0.f);
                s[i][r] = fmaf(v, wo, s[i][r]);
            }
    }
    #pragma unroll
    for (int i = 0; i < 4; ++i)
        #pragma unroll
        for (int r = 0; r < 4; ++r) {
            float v = s[i][r];
            v += __shfl_xor(v, 1, 64);
            v += __shfl_xor(v, 2, 64);
            v += __shfl_xor(v, 4, 64);
            v += __shfl_xor(v, 8, 64);
            s[i][r] = v;
        }
    if (lr16 == 0) {
        #pragma unroll
        for (int i = 0; i < 4; ++i) {
            const int mbase = m0 + wm * 64 + i * 16 + q * 4;
            #pragma unroll
            for (int r = 0; r < 4; ++r)
                atomicAdd(&outp[mbase + r], s[i][r]);
        }
    }
}

// ---------------------------------------------------------------------------
// out[b] = sigmoid(outp[b] + b_out)
// ---------------------------------------------------------------------------
__global__ __launch_bounds__(256) void sigmoid_kernel(
    const float* __restrict__ outp, const float* __restrict__ b_out,
    float* __restrict__ out)
{
    const int b = blockIdx.x * 256 + threadIdx.x;
    out[b] = 1.f / (1.f + expf(-(outp[b] + b_out[0])));
}

// ---------------------------------------------------------------------------
extern "C" void kernel_launch(void* const* d_in, const int* in_sizes, int n_in,
                              void* d_out, int out_size, void* d_ws, size_t ws_size,
                              hipStream_t stream)
{
    const int*   x     = (const int*)  d_in[0];
    const float* emb   = (const float*)d_in[1];
    const float* w_c   = (const float*)d_in[2];
    const float* b_c   = (const float*)d_in[3];
    const float* g_c   = (const float*)d_in[4];
    const float* be_c  = (const float*)d_in[5];
    const float* w0    = (const float*)d_in[6];
    const float* b0    = (const float*)d_in[7];
    const float* g0    = (const float*)d_in[8];
    const float* be0   = (const float*)d_in[9];
    const float* w1    = (const float*)d_in[10];
    const float* b1    = (const float*)d_in[11];
    const float* g1    = (const float*)d_in[12];
    const float* be1   = (const float*)d_in[13];
    const float* w_out = (const float*)d_in[14];
    const float* b_out = (const float*)d_in[15];
    float* out = (float*)d_out;

    // workspace layout (~57 MB)
    u16*   zb    = (u16*)d_ws;                          // B*640*2  = 20.97 MB
    u16*   w0b   = zb    + (size_t)B_SZ * KP0;          // 1.31 MB
    u16*   h0b   = w0b   + (size_t)N0 * KP0;            // 33.55 MB
    u16*   w1b   = h0b   + (size_t)B_SZ * N0;           // 1.05 MB
    u16*   wcb   = w1b   + (size_t)N1 * N0;             // 0.06 MB
    float* outp  = (float*)(wcb + (size_t)NCP * KP0);   // 64 KB
    float* bcp   = outp + B_SZ;
    float* gcp   = bcp + NCP;
    float* becp  = gcp + NCP;

    prep_all_kernel<<<(PREP_TOT + 255) / 256, 256, 0, stream>>>(
        w0, w1, w_c, b_c, g_c, be_c, w0b, w1b, wcb, bcp, gcp, becp, outp);

    fused_controller_kernel<<<B_SZ / CBR, 256, 0, stream>>>(
        x, emb, wcb, bcp, gcp, becp, zb);

    gemm0_256_kernel<<<dim3(B_SZ / 256, N0 / 128), 256, 0, stream>>>(
        zb, w0b, b0, g0, be0, h0b, B_SZ, N0, KP0);

    gemm1_fused_out_kernel<<<dim3(B_SZ / 128, N1 / 128), 256, 0, stream>>>(
        h0b, w1b, b1, g1, be1, B_SZ, N1, N0, w_out, outp);

    sigmoid_kernel<<<B_SZ / 256, 256, 0, stream>>>(outp, b_out, out);
}

// Round 11
// 220.667 us; speedup vs baseline: 1.1654x; 1.0357x over previous
//
#include <hip/hip_runtime.h>
#include <math.h>

#define B_SZ 16384
#define F_N 39
#define V_N 30000
#define D_N 16
#define K_SEL 20
#define FD 624     // F_N * D_N
#define KP0 640    // controller/GEMM0 K padded to multiple of 32
#define NCP 48     // controller GEMM padded N (>= 39, 3 n-tiles of 16)
#define N0 1024
#define N1 512
#define CBR 16     // batch rows per fused-controller block
#define ALD 648    // LDS row stride (u16)

typedef unsigned short u16;
typedef __attribute__((ext_vector_type(8))) short bf16x8;
typedef __attribute__((ext_vector_type(8))) unsigned short u16x8;
typedef __attribute__((ext_vector_type(4))) float f32x4;
typedef __attribute__((ext_vector_type(4))) unsigned short u16x4;

__device__ __forceinline__ u16 f2bf(float v) {
    union { float f; unsigned u; } x; x.f = v;
    unsigned r = x.u + 0x7fff + ((x.u >> 16) & 1);   // RNE
    return (u16)(r >> 16);
}
__device__ __forceinline__ float bf2f(u16 v) {
    union { unsigned u; float f; } x; x.u = ((unsigned)v) << 16;
    return x.f;
}

#define GLD16(gp, lp) __builtin_amdgcn_global_load_lds( \
    (const __attribute__((address_space(1))) unsigned int*)(gp), \
    (__attribute__((address_space(3))) unsigned int*)(lp), 16, 0, 0)

// ---------------------------------------------------------------------------
// Merged prep: w0 permute+convert, w1 convert, wc permute+convert, bn params,
// outp zeroing.
// ---------------------------------------------------------------------------
#define PREP_W0 (N0 * KP0)                 // 655360
#define PREP_W1 (N1 * N0)                  // 524288
#define PREP_WC (NCP * KP0)                // 30720
#define PREP_TOT (PREP_W0 + PREP_W1 + PREP_WC + 3 * NCP + B_SZ)

__global__ __launch_bounds__(256) void prep_all_kernel(
    const float* __restrict__ w0, const float* __restrict__ w1,
    const float* __restrict__ w_c, const float* __restrict__ b_c,
    const float* __restrict__ g_c, const float* __restrict__ be_c,
    u16* __restrict__ w0b, u16* __restrict__ w1b, u16* __restrict__ wcb,
    float* __restrict__ bcp, float* __restrict__ gcp, float* __restrict__ becp,
    float* __restrict__ outp)
{
    int i = blockIdx.x * blockDim.x + threadIdx.x;
    if (i < PREP_W0) {
        int n = i / KP0, kk = i - n * KP0;
        float v = 0.f;
        if (kk < FD) v = w0[n * FD + (kk & 15) * F_N + (kk >> 4)];
        w0b[i] = f2bf(v);
        return;
    }
    i -= PREP_W0;
    if (i < PREP_W1) { w1b[i] = f2bf(w1[i]); return; }
    i -= PREP_W1;
    if (i < PREP_WC) {
        int n = i / KP0, kk = i - n * KP0;
        float v = 0.f;
        if (n < F_N && kk < FD) v = w_c[n * FD + (kk & 15) * F_N + (kk >> 4)];
        wcb[i] = f2bf(v);
        return;
    }
    i -= PREP_WC;
    if (i < 3 * NCP) {
        int which = i / NCP, n = i - which * NCP;
        float v = 0.f;
        if (n < F_N) v = (which == 0) ? b_c[n] : (which == 1) ? g_c[n] : be_c[n];
        ((which == 0) ? bcp : (which == 1) ? gcp : becp)[n] = v;
        return;
    }
    i -= 3 * NCP;
    if (i < B_SZ) outp[i] = 0.f;
}

// ---------------------------------------------------------------------------
// Fused controller: gather -> LDS (hoisted x-loads), 16x48 MFMA split-K GEMM,
// all-wave reduce, wave-sliced bn/softmax/top-K rank, select-scale -> zb.
// ---------------------------------------------------------------------------
__global__ __launch_bounds__(256) void fused_controller_kernel(
    const int* __restrict__ x, const float* __restrict__ emb_table,
    const u16* __restrict__ wcb, const float* __restrict__ bcp,
    const float* __restrict__ gcp, const float* __restrict__ becp,
    u16* __restrict__ zb)
{
    __shared__ __align__(16) u16 Al[CBR * ALD];
    __shared__ float vv[CBR][49];
    __shared__ f32x4 part[4][64][3];
    __shared__ float selw[CBR][F_N];

    const int t    = threadIdx.x;
    const int wave = t >> 6;
    const int lane = t & 63;
    const int b0   = blockIdx.x * CBR;

    // ---- gather: 3 explicit slots, all x-loads hoisted before emb-loads ----
    {
        const int p0 = t, p1 = t + 256, p2 = t + 512;
        const int xi0 = x[b0 * F_N + p0];
        const int xi1 = x[b0 * F_N + p1];
        const int xi2 = (p2 < CBR * F_N) ? x[b0 * F_N + p2] : 0;
        const int pp[3] = { p0, p1, p2 };
        const int xx[3] = { xi0, xi1, xi2 };
        #pragma unroll
        for (int s = 0; s < 3; ++s) {
            const int p = pp[s];
            if (p < CBR * F_N) {
                const int row = p / F_N;
                const int f   = p - row * F_N;
                const float4* src =
                    (const float4*)(emb_table + (size_t)(xx[s] + f * V_N) * D_N);
                float4 v0 = src[0], v1 = src[1], v2 = src[2], v3 = src[3];
                u16x8 o0 = { f2bf(v0.x), f2bf(v0.y), f2bf(v0.z), f2bf(v0.w),
                             f2bf(v1.x), f2bf(v1.y), f2bf(v1.z), f2bf(v1.w) };
                u16x8 o1 = { f2bf(v2.x), f2bf(v2.y), f2bf(v2.z), f2bf(v2.w),
                             f2bf(v3.x), f2bf(v3.y), f2bf(v3.z), f2bf(v3.w) };
                *(u16x8*)&Al[row * ALD + f * D_N]     = o0;
                *(u16x8*)&Al[row * ALD + f * D_N + 8] = o1;
            }
        }
    }
    __syncthreads();

    const int m = lane & 15;
    const int q = lane >> 4;
    f32x4 acc0 = {}, acc1 = {}, acc2 = {};
    {
        const u16* ap  = &Al[m * ALD + wave * 160 + q * 8];
        const u16* bp0 = wcb + (size_t)(0  + m) * KP0 + wave * 160 + q * 8;
        const u16* bp1 = wcb + (size_t)(16 + m) * KP0 + wave * 160 + q * 8;
        const u16* bp2 = wcb + (size_t)(32 + m) * KP0 + wave * 160 + q * 8;
        #pragma unroll
        for (int k = 0; k < 5; ++k) {
            bf16x8 af = *(const bf16x8*)ap;
            bf16x8 b0 = *(const bf16x8*)bp0;
            bf16x8 b1 = *(const bf16x8*)bp1;
            bf16x8 b2 = *(const bf16x8*)bp2;
            acc0 = __builtin_amdgcn_mfma_f32_16x16x32_bf16(af, b0, acc0, 0, 0, 0);
            acc1 = __builtin_amdgcn_mfma_f32_16x16x32_bf16(af, b1, acc1, 0, 0, 0);
            acc2 = __builtin_amdgcn_mfma_f32_16x16x32_bf16(af, b2, acc2, 0, 0, 0);
            ap += 32; bp0 += 32; bp1 += 32; bp2 += 32;
        }
    }
    part[wave][lane][0] = acc0;
    part[wave][lane][1] = acc1;
    part[wave][lane][2] = acc2;
    __syncthreads();

    {
        f32x4 r0 = part[0][lane][0] + part[1][lane][0] + part[2][lane][0] + part[3][lane][0];
        f32x4 r1 = part[0][lane][1] + part[1][lane][1] + part[2][lane][1] + part[3][lane][1];
        f32x4 r2 = part[0][lane][2] + part[1][lane][2] + part[2][lane][2] + part[3][lane][2];

        const float rs = rsqrtf(1.0f + 1e-5f);
        if (q == wave) {
            #pragma unroll
            for (int j = 0; j < 3; ++j) {
                const f32x4 a = (j == 0) ? r0 : (j == 1) ? r1 : r2;
                const int n = j * 16 + m;
                const float gn = gcp[n] * rs;
                const float bn = becp[n];
                const float bi = bcp[n];
                #pragma unroll
                for (int r = 0; r < 4; ++r)
                    vv[wave * 4 + r][n] = fmaxf(fmaf(gn, a[r] + bi, bn), 0.f);
            }
        }
    }
    __syncthreads();

    {
        const int row = wave * 4 + (lane >> 4);
        const int fl  = lane & 15;
        float e[3] = {0.f, 0.f, 0.f};
        float mloc = -1e30f;
        #pragma unroll
        for (int it = 0; it < 3; ++it) {
            const int f = fl + 16 * it;
            if (f < F_N) { e[it] = vv[row][f]; mloc = fmaxf(mloc, e[it]); }
        }
        mloc = fmaxf(mloc, __shfl_xor(mloc, 1, 64));
        mloc = fmaxf(mloc, __shfl_xor(mloc, 2, 64));
        mloc = fmaxf(mloc, __shfl_xor(mloc, 4, 64));
        mloc = fmaxf(mloc, __shfl_xor(mloc, 8, 64));
        float sloc = 0.f;
        #pragma unroll
        for (int it = 0; it < 3; ++it) {
            const int f = fl + 16 * it;
            if (f < F_N) { e[it] = expf(e[it] - mloc); sloc += e[it]; }
        }
        sloc += __shfl_xor(sloc, 1, 64);
        sloc += __shfl_xor(sloc, 2, 64);
        sloc += __shfl_xor(sloc, 4, 64);
        sloc += __shfl_xor(sloc, 8, 64);
        const float inv = 1.f / sloc;
        #pragma unroll
        for (int it = 0; it < 3; ++it) {
            const int f = fl + 16 * it;
            if (f < F_N) vv[row][f] = e[it];
        }

        int rank[3] = {};
        for (int gg = 0; gg < F_N; ++gg) {
            const float o = vv[row][gg];
            #pragma unroll
            for (int it = 0; it < 3; ++it) {
                const int f = fl + 16 * it;
                if (f < F_N)
                    rank[it] += (o > e[it] || (o == e[it] && gg < f)) ? 1 : 0;
            }
        }
        #pragma unroll
        for (int it = 0; it < 3; ++it) {
            const int f = fl + 16 * it;
            if (f < F_N)
                selw[row][f] = (rank[it] < K_SEL) ? e[it] * inv : 0.f;
        }
    }
    __syncthreads();

    for (int gp = t; gp < CBR * 40; gp += 256) {
        const int row  = gp & 15;
        const int slot = gp >> 4;
        u16* dst = zb + (size_t)(b0 + row) * KP0 + slot * D_N;
        u16x8 o0 = {0,0,0,0,0,0,0,0}, o1 = {0,0,0,0,0,0,0,0};
        if (slot < F_N) {
            const float w = selw[row][slot];
            u16x8 a0 = *(u16x8*)&Al[row * ALD + slot * D_N];
            u16x8 a1 = *(u16x8*)&Al[row * ALD + slot * D_N + 8];
            #pragma unroll
            for (int k = 0; k < 8; ++k) {
                o0[k] = f2bf(bf2f(a0[k]) * w);
                o1[k] = f2bf(bf2f(a1[k]) * w);
            }
        }
        *(u16x8*)dst = o0;
        *(u16x8*)(dst + 8) = o1;
    }
}

// ---------------------------------------------------------------------------
// MFMA GEMM, 128x128 tile, BK=32, 3-stage LDS pipeline (prefetch distance 2):
// GLD issued at iter i targets buffer (i+2)%3 and has two full compute
// phases to land before its drain at barrier i+2. Buffer (i+2)%3 == (i-1)%3
// was consumed at i-1; the vmcnt(0) drain at barrier i+1 guarantees it is
// fully written one iteration before reuse.
// MODE 0: C = relu(bn(A@W^T+bias)) stored bf16.
// MODE 1: fused w_out dot + shuffle reduce + atomicAdd row partials.
// ---------------------------------------------------------------------------
template<int MODE>
__global__ __launch_bounds__(256) void gemm_mfma_bn_relu(
    const u16* __restrict__ A, const u16* __restrict__ W,
    const float* __restrict__ bias, const float* __restrict__ g,
    const float* __restrict__ be, u16* __restrict__ Cout,
    int M, int N, int Kp,
    const float* __restrict__ w_out, float* __restrict__ outp)
{
    __shared__ __align__(16) u16 As[3][128 * 32];
    __shared__ __align__(16) u16 Bs[3][128 * 32];

    const int t    = threadIdx.x;
    const int wave = t >> 6;
    const int lane = t & 63;
    const int wm   = wave >> 1, wn = wave & 1;
    const int m0   = blockIdx.x * 128;   // M fastest -> XCD-local A reuse
    const int n0   = blockIdx.y * 128;

    const int lr    = lane >> 2;
    const int swz_u = (lane & 3) ^ ((lane >> 3) & 3);
    const u16* gA0 = A + (size_t)(m0 + wave * 32 + lr) * Kp + swz_u * 8;
    const u16* gB0 = W + (size_t)(n0 + wave * 32 + lr) * Kp + swz_u * 8;
    const size_t kstep16 = 16 * (size_t)Kp;
    const int oA0 = (wave * 32) * 32;
    const int oA1 = (wave * 32 + 16) * 32;

    const int q    = lane >> 4;
    const int lr16 = lane & 15;

    int aoff[4], boff[4];
    #pragma unroll
    for (int i = 0; i < 4; ++i) {
        int ra = wm * 64 + i * 16 + lr16;
        aoff[i] = ra * 32 + ((q ^ ((ra >> 1) & 3)) * 8);
        int rb = wn * 64 + i * 16 + lr16;
        boff[i] = rb * 32 + ((q ^ ((rb >> 1) & 3)) * 8);
    }

    // prologue: stage iters 0 and 1 into buffers 0 and 1
    GLD16(gA0,           &As[0][oA0]);
    GLD16(gA0 + kstep16, &As[0][oA1]);
    GLD16(gB0,           &Bs[0][oA0]);
    GLD16(gB0 + kstep16, &Bs[0][oA1]);
    gA0 += 32; gB0 += 32;
    GLD16(gA0,           &As[1][oA0]);
    GLD16(gA0 + kstep16, &As[1][oA1]);
    GLD16(gB0,           &Bs[1][oA0]);
    GLD16(gB0 + kstep16, &Bs[1][oA1]);
    gA0 += 32; gB0 += 32;

    f32x4 acc[4][4] = {};
    int cur = 0, stg = 2;

    for (int k0 = 0; k0 < Kp; k0 += 32) {
        __syncthreads();   // drains GLDs; cur (and cur+1) buffers are ready
        if (k0 + 64 < Kp) {
            GLD16(gA0,           &As[stg][oA0]);
            GLD16(gA0 + kstep16, &As[stg][oA1]);
            GLD16(gB0,           &Bs[stg][oA0]);
            GLD16(gB0 + kstep16, &Bs[stg][oA1]);
            gA0 += 32; gB0 += 32;
        }

        bf16x8 af[4], bfr[4];
        #pragma unroll
        for (int i = 0; i < 4; ++i) af[i]  = *(const bf16x8*)&As[cur][aoff[i]];
        #pragma unroll
        for (int j = 0; j < 4; ++j) bfr[j] = *(const bf16x8*)&Bs[cur][boff[j]];

        #pragma unroll
        for (int i = 0; i < 4; ++i)
            #pragma unroll
            for (int j = 0; j < 4; ++j)
                acc[i][j] = __builtin_amdgcn_mfma_f32_16x16x32_bf16(
                    af[i], bfr[j], acc[i][j], 0, 0, 0);

        cur = (cur == 2) ? 0 : cur + 1;
        stg = (stg == 2) ? 0 : stg + 1;
    }

    const float rs = rsqrtf(1.0f + 1e-5f);
    if (MODE == 0) {
        #pragma unroll
        for (int j = 0; j < 4; ++j) {
            const int n = n0 + wn * 64 + j * 16 + lr16;
            const float bn_g = g[n] * rs;
            const float bn_b = be[n];
            const float bi   = bias[n];
            #pragma unroll
            for (int i = 0; i < 4; ++i) {
                const int mbase = m0 + wm * 64 + i * 16 + q * 4;
                #pragma unroll
                for (int r = 0; r < 4; ++r) {
                    float v = acc[i][j][r] + bi;
                    v = fmaxf(fmaf(bn_g, v, bn_b), 0.f);
                    Cout[(size_t)(mbase + r) * N + n] = f2bf(v);
                }
            }
        }
    } else {
        float s[4][4] = {};
        #pragma unroll
        for (int j = 0; j < 4; ++j) {
            const int n = n0 + wn * 64 + j * 16 + lr16;
            const float bn_g = g[n] * rs;
            const float bn_b = be[n];
            const float bi   = bias[n];
            const float wo   = w_out[n];
            #pragma unroll
            for (int i = 0; i < 4; ++i)
                #pragma unroll
                for (int r = 0; r < 4; ++r) {
                    float v = acc[i][j][r] + bi;
                    v = fmaxf(fmaf(bn_g, v, bn_b), 0.f);
                    s[i][r] = fmaf(v, wo, s[i][r]);
                }
        }
        #pragma unroll
        for (int i = 0; i < 4; ++i)
            #pragma unroll
            for (int r = 0; r < 4; ++r) {
                float v = s[i][r];
                v += __shfl_xor(v, 1, 64);
                v += __shfl_xor(v, 2, 64);
                v += __shfl_xor(v, 4, 64);
                v += __shfl_xor(v, 8, 64);
                s[i][r] = v;
            }
        if (lr16 == 0) {
            #pragma unroll
            for (int i = 0; i < 4; ++i) {
                const int mbase = m0 + wm * 64 + i * 16 + q * 4;
                #pragma unroll
                for (int r = 0; r < 4; ++r)
                    atomicAdd(&outp[mbase + r], s[i][r]);
            }
        }
    }
}

// ---------------------------------------------------------------------------
// out[b] = sigmoid(outp[b] + b_out)
// ---------------------------------------------------------------------------
__global__ __launch_bounds__(256) void sigmoid_kernel(
    const float* __restrict__ outp, const float* __restrict__ b_out,
    float* __restrict__ out)
{
    const int b = blockIdx.x * 256 + threadIdx.x;
    out[b] = 1.f / (1.f + expf(-(outp[b] + b_out[0])));
}

// ---------------------------------------------------------------------------
extern "C" void kernel_launch(void* const* d_in, const int* in_sizes, int n_in,
                              void* d_out, int out_size, void* d_ws, size_t ws_size,
                              hipStream_t stream)
{
    const int*   x     = (const int*)  d_in[0];
    const float* emb   = (const float*)d_in[1];
    const float* w_c   = (const float*)d_in[2];
    const float* b_c   = (const float*)d_in[3];
    const float* g_c   = (const float*)d_in[4];
    const float* be_c  = (const float*)d_in[5];
    const float* w0    = (const float*)d_in[6];
    const float* b0    = (const float*)d_in[7];
    const float* g0    = (const float*)d_in[8];
    const float* be0   = (const float*)d_in[9];
    const float* w1    = (const float*)d_in[10];
    const float* b1    = (const float*)d_in[11];
    const float* g1    = (const float*)d_in[12];
    const float* be1   = (const float*)d_in[13];
    const float* w_out = (const float*)d_in[14];
    const float* b_out = (const float*)d_in[15];
    float* out = (float*)d_out;

    // workspace layout (~57 MB)
    u16*   zb    = (u16*)d_ws;                          // B*640*2  = 20.97 MB
    u16*   w0b   = zb    + (size_t)B_SZ * KP0;          // 1.31 MB
    u16*   h0b   = w0b   + (size_t)N0 * KP0;            // 33.55 MB
    u16*   w1b   = h0b   + (size_t)B_SZ * N0;           // 1.05 MB
    u16*   wcb   = w1b   + (size_t)N1 * N0;             // 0.06 MB
    float* outp  = (float*)(wcb + (size_t)NCP * KP0);   // 64 KB
    float* bcp   = outp + B_SZ;
    float* gcp   = bcp + NCP;
    float* becp  = gcp + NCP;

    prep_all_kernel<<<(PREP_TOT + 255) / 256, 256, 0, stream>>>(
        w0, w1, w_c, b_c, g_c, be_c, w0b, w1b, wcb, bcp, gcp, becp, outp);

    fused_controller_kernel<<<B_SZ / CBR, 256, 0, stream>>>(
        x, emb, wcb, bcp, gcp, becp, zb);

    gemm_mfma_bn_relu<0><<<dim3(B_SZ / 128, N0 / 128), 256, 0, stream>>>(
        zb, w0b, b0, g0, be0, h0b, B_SZ, N0, KP0, nullptr, nullptr);

    gemm_mfma_bn_relu<1><<<dim3(B_SZ / 128, N1 / 128), 256, 0, stream>>>(
        h0b, w1b, b1, g1, be1, nullptr, B_SZ, N1, N0, w_out, outp);

    sigmoid_kernel<<<B_SZ / 256, 256, 0, stream>>>(outp, b_out, out);
}